// Round 3
// baseline (507.184 us; speedup 1.0000x reference)
//
#include <hip/hip_runtime.h>
#include <stdint.h>

// ---------------------------------------------------------------------------
// Mamba block on MI355X (gfx950).  B=8, L=1024, D_MODEL=512, D_INNER=1024,
// D2=512, DT_RANK=32, N_STATE=16, K_CONV=4, HIDDEN=2048.  M = B*L = 8192.
// All activations (b, l, channel) row-major; every matmul is A(M,K) x W(N,K)^T.
//
// GEMM strategy (R3): barrier-free register-direct MFMA. Each wave owns an
// MI x 64 output tile, loads its A/B fragments straight from global memory
// (global_load_dwordx4, 16 rows x 64 B per instruction), double-buffered in
// registers with static indices so loads and MFMAs interleave in one
// instruction stream — no __syncthreads, no vmcnt(0) drain.
// ---------------------------------------------------------------------------

#define MROWS 8192
#define LSEQ 1024
#define DMODEL 512
#define DINNER 1024
#define D2 512
#define NSTATE 16
#define HIDDEN 2048
#define NCHUNK 16
#define LCHUNK 64

typedef short short8 __attribute__((ext_vector_type(8)));
typedef float floatx4 __attribute__((ext_vector_type(4)));

__device__ __forceinline__ unsigned short f2bf(float f) {
    unsigned int u = __float_as_uint(f);
    u = (u + 0x7fffu + ((u >> 16) & 1u)) >> 16;
    return (unsigned short)u;
}
__device__ __forceinline__ float bf2f(unsigned short u) {
    return __uint_as_float(((unsigned int)u) << 16);
}

// ---------------------------------------------------------------------------
// Weight fp32 -> bf16 conversion (all 6 matmul weights in one kernel)
// ---------------------------------------------------------------------------
__global__ __launch_bounds__(256) void cvt_weights(
    const float* __restrict__ w0, const float* __restrict__ w1,
    const float* __restrict__ w2, const float* __restrict__ w3,
    const float* __restrict__ w4, const float* __restrict__ w5,
    unsigned short* __restrict__ o0, unsigned short* __restrict__ o1,
    unsigned short* __restrict__ o2, unsigned short* __restrict__ o3,
    unsigned short* __restrict__ o4, unsigned short* __restrict__ o5)
{
    int i = blockIdx.x * 256 + threadIdx.x;
    if (i < 524288)            o0[i]           = f2bf(w0[i]);
    else if (i < 557056)       o1[i - 524288]  = f2bf(w1[i - 524288]);
    else if (i < 573440)       o2[i - 557056]  = f2bf(w2[i - 557056]);
    else if (i < 1097728)      o3[i - 573440]  = f2bf(w3[i - 573440]);
    else if (i < 2146304)      o4[i - 1097728] = f2bf(w4[i - 1097728]);
    else if (i < 3194880)      o5[i - 2146304] = f2bf(w5[i - 2146304]);
}

// ---------------------------------------------------------------------------
// LayerNorm over 512 channels; one block (256 thr) per row; bf16 output.
// ---------------------------------------------------------------------------
__global__ __launch_bounds__(256) void ln_kernel(
    const float* __restrict__ x, const float* __restrict__ w,
    const float* __restrict__ b, unsigned short* __restrict__ out)
{
    int row = blockIdx.x;
    int tid = threadIdx.x;
    const float* xr = x + (size_t)row * DMODEL;
    float2 v = ((const float2*)xr)[tid];
    float s = v.x + v.y;
    float ss = v.x * v.x + v.y * v.y;
    #pragma unroll
    for (int off = 32; off > 0; off >>= 1) {
        s += __shfl_down(s, off);
        ss += __shfl_down(ss, off);
    }
    __shared__ float red[10];
    int wv = tid >> 6, ln = tid & 63;
    if (ln == 0) { red[wv] = s; red[wv + 4] = ss; }
    __syncthreads();
    if (tid == 0) {
        float S = red[0] + red[1] + red[2] + red[3];
        float SS = red[4] + red[5] + red[6] + red[7];
        float mean = S * (1.f / DMODEL);
        float var = SS * (1.f / DMODEL) - mean * mean;
        red[8] = mean;
        red[9] = rsqrtf(var + 1e-5f);
    }
    __syncthreads();
    float mean = red[8], rstd = red[9];
    float2 wv2 = ((const float2*)w)[tid];
    float2 bv2 = ((const float2*)b)[tid];
    unsigned short* o = out + (size_t)row * DMODEL + tid * 2;
    o[0] = f2bf((v.x - mean) * rstd * wv2.x + bv2.x);
    o[1] = f2bf((v.y - mean) * rstd * wv2.y + bv2.y);
}

// ---------------------------------------------------------------------------
// Register-direct bf16 MFMA GEMM:  C(M,N) = A(M,K) * W(N,K)^T, fp32 acc.
// One wave per MI x 64 output tile (MI in {16,32,64}); 256-thread blocks hold
// 4 independent waves (consecutive waves share the same 64 B-columns -> L1
// reuse of the weight fragments). Per 32-wide k-step a wave loads AI+4
// dwordx4 fragments and issues AI*4 MFMAs; two register buffers with static
// indices let the compiler keep loads in flight across k-steps.
// A-fragment for MFMA 16x16x32: lane(lr,lq) holds A[row0+lr][k + lq*8 .. +8].
// ---------------------------------------------------------------------------
#define M_F32 0
#define M_F32_BF16 1
#define M_SOFTPLUS_F32 2
#define M_RES_F32 3
#define M_GELU_BF16 4
#define M_BIAS_RES_F32 5
#define M_BF16 6

template <int MODE, int MI>
__global__ __launch_bounds__(256) void gemm_rr(
    const unsigned short* __restrict__ A, int lda,
    const unsigned short* __restrict__ B, int ldb,
    int M, int N, int K,
    float* __restrict__ outF, unsigned short* __restrict__ outB, int ldc,
    const float* __restrict__ bias, const float* __restrict__ res)
{
    constexpr int AI = MI / 16;
    int tid = threadIdx.x;
    int lane = tid & 63;
    int lr = lane & 15;
    int lq = lane >> 4;
    int w = blockIdx.x * 4 + (tid >> 6);
    int WM = M / MI;
    int wmi = w & (WM - 1);          // WM is a power of two for all calls
    int wni = w / WM;
    int m0 = wmi * MI;
    int n0 = wni * 64;

    const unsigned short* Ab = A + (size_t)(m0 + lr) * lda + lq * 8;
    const unsigned short* Bb = B + (size_t)(n0 + lr) * ldb + lq * 8;

    short8 afr[2][AI], bfr[2][4];
    floatx4 zero4 = {0.f, 0.f, 0.f, 0.f};
    floatx4 acc[AI][4];
    #pragma unroll
    for (int i = 0; i < AI; i++)
        #pragma unroll
        for (int j = 0; j < 4; j++) acc[i][j] = zero4;

    auto loadk = [&](int buf, int kk) {
        #pragma unroll
        for (int i = 0; i < AI; i++)
            afr[buf][i] = *(const short8*)(Ab + (size_t)i * 16 * lda + kk);
        #pragma unroll
        for (int j = 0; j < 4; j++)
            bfr[buf][j] = *(const short8*)(Bb + (size_t)j * 16 * ldb + kk);
    };
    auto mm = [&](int buf) {
        #pragma unroll
        for (int i = 0; i < AI; i++)
            #pragma unroll
            for (int j = 0; j < 4; j++)
                acc[i][j] = __builtin_amdgcn_mfma_f32_16x16x32_bf16(
                    afr[buf][i], bfr[buf][j], acc[i][j], 0, 0, 0);
    };

    const int T = K >> 5;            // number of 32-wide k-steps
    loadk(0, 0);
    int t = 1;
    for (; t + 1 < T; t += 2) {      // static buffer indices -> stays in regs
        loadk(1, t * 32);
        mm(0);
        loadk(0, (t + 1) * 32);
        mm(1);
    }
    if (t < T) {                     // T even: one trailing step in buf 1
        loadk(1, t * 32);
        mm(0);
        mm(1);
    } else {                         // T odd (incl. T==1)
        mm(0);
    }

    // epilogue: C/D layout col = lane&15, row = (lane>>4)*4 + reg
    #pragma unroll
    for (int j = 0; j < 4; j++) {
        int col = n0 + j * 16 + lr;
        #pragma unroll
        for (int i = 0; i < AI; i++) {
            #pragma unroll
            for (int r = 0; r < 4; r++) {
                int rowm = m0 + i * 16 + lq * 4 + r;
                float v = acc[i][j][r];
                size_t o = (size_t)rowm * ldc + col;
                if (MODE == M_F32) {
                    outF[o] = v;
                } else if (MODE == M_BF16) {
                    outB[o] = f2bf(v);
                } else if (MODE == M_F32_BF16) {
                    outF[o] = v;
                    outB[o] = f2bf(v);
                } else if (MODE == M_SOFTPLUS_F32) {
                    float tb = v + bias[col];
                    outF[o] = (tb > 20.f) ? tb : log1pf(__expf(tb));
                } else if (MODE == M_RES_F32) {
                    outF[o] = v + res[o];
                } else if (MODE == M_GELU_BF16) {
                    float tb = v + bias[col];
                    outB[o] = f2bf(0.5f * tb * (1.f + erff(tb * 0.70710678118f)));
                } else { // M_BIAS_RES_F32
                    outF[o] = v + bias[col] + res[o];
                }
            }
        }
    }
}

// ---------------------------------------------------------------------------
// Depthwise conv (K=4, pad 1 left / 2 right) + SiLU on both halves of xz.
// xz: (b,l,1024) bf16.  Writes xh fp32 + bf16, and zh bf16 into outbuf[:,512:].
// ---------------------------------------------------------------------------
__global__ __launch_bounds__(256) void conv_silu(
    const unsigned short* __restrict__ xz, const float* __restrict__ cwx,
    const float* __restrict__ cwz, float* __restrict__ xh_f,
    unsigned short* __restrict__ xh_b, unsigned short* __restrict__ outbuf)
{
    int idx = blockIdx.x * 256 + threadIdx.x;   // (b*L + l)*512 + d
    int d = idx & 511;
    int bl = idx >> 9;
    int l = bl & (LSEQ - 1);
    float ax = 0.f, az = 0.f;
    #pragma unroll
    for (int k = 0; k < 4; k++) {
        int ll = l + k - 1;
        if (ll >= 0 && ll < LSEQ) {
            const unsigned short* src = xz + (size_t)(bl + k - 1) * DINNER;
            ax += cwx[d * 4 + k] * bf2f(src[d]);
            az += cwz[d * 4 + k] * bf2f(src[512 + d]);
        }
    }
    ax = ax / (1.f + __expf(-ax));
    az = az / (1.f + __expf(-az));
    xh_f[idx] = ax;
    xh_b[idx] = f2bf(ax);
    outbuf[(size_t)bl * DINNER + 512 + d] = f2bf(az);
}

// ---------------------------------------------------------------------------
// Selective scan, 3-phase chunked linear recurrence.
// ---------------------------------------------------------------------------
__global__ __launch_bounds__(256) void scan_phase1(
    const float* __restrict__ delta, const float* __restrict__ u,
    const float* __restrict__ xdbl, const float* __restrict__ A_log,
    float* __restrict__ S, float* __restrict__ P)
{
    int bx = blockIdx.x;                 // 8 b * 16 c * 2 halves = 256
    int b = bx >> 5, rem = bx & 31, c = rem >> 1, half = rem & 1;
    int d = half * 256 + threadIdx.x;
    float A[NSTATE], h[NSTATE];
    #pragma unroll
    for (int n = 0; n < NSTATE; n++) {
        A[n] = -__expf(A_log[d * NSTATE + n]);
        h[n] = 0.f;
    }
    float sdt = 0.f;
    int l0 = c * LCHUNK;
    for (int l = l0; l < l0 + LCHUNK; ++l) {
        size_t idx = (size_t)(b * LSEQ + l);
        float dv = delta[idx * D2 + d];
        float uv = u[idx * D2 + d];
        float du = dv * uv;
        const float4* Bp = (const float4*)(xdbl + idx * 64 + 32);
        float4 B0 = Bp[0], B1 = Bp[1], B2 = Bp[2], B3 = Bp[3];
        float Bn[16] = {B0.x, B0.y, B0.z, B0.w, B1.x, B1.y, B1.z, B1.w,
                        B2.x, B2.y, B2.z, B2.w, B3.x, B3.y, B3.z, B3.w};
        sdt += dv;
        #pragma unroll
        for (int n = 0; n < NSTATE; n++)
            h[n] = __expf(dv * A[n]) * h[n] + du * Bn[n];
    }
    size_t o = ((size_t)(b * D2 + d)) * (NCHUNK * NSTATE) + c * NSTATE;
    #pragma unroll
    for (int n = 0; n < NSTATE; n++) {
        S[o + n] = h[n];
        P[o + n] = __expf(sdt * A[n]);
    }
}

__global__ __launch_bounds__(256) void scan_phase2(
    const float* __restrict__ S, const float* __restrict__ P,
    float* __restrict__ hin)
{
    int gid = blockIdx.x * 256 + threadIdx.x;   // 65536 = 8*512*16
    int n = gid & 15, d = (gid >> 4) & 511, b = gid >> 13;
    size_t base = ((size_t)(b * D2 + d)) * (NCHUNK * NSTATE) + n;
    float h = 0.f;
    for (int c = 0; c < NCHUNK; c++) {
        size_t o = base + c * NSTATE;
        hin[o] = h;
        h = P[o] * h + S[o];
    }
}

__global__ __launch_bounds__(256) void scan_phase3(
    const float* __restrict__ delta, const float* __restrict__ u,
    const float* __restrict__ xdbl, const float* __restrict__ hin,
    const float* __restrict__ A_log, const float* __restrict__ Dvec,
    unsigned short* __restrict__ outbuf)
{
    int bx = blockIdx.x;
    int b = bx >> 5, rem = bx & 31, c = rem >> 1, half = rem & 1;
    int d = half * 256 + threadIdx.x;
    float A[NSTATE], h[NSTATE];
    size_t hb = ((size_t)(b * D2 + d)) * (NCHUNK * NSTATE) + c * NSTATE;
    #pragma unroll
    for (int n = 0; n < NSTATE; n++) {
        A[n] = -__expf(A_log[d * NSTATE + n]);
        h[n] = hin[hb + n];
    }
    float Dd = Dvec[d];
    int l0 = c * LCHUNK;
    for (int l = l0; l < l0 + LCHUNK; ++l) {
        size_t idx = (size_t)(b * LSEQ + l);
        float dv = delta[idx * D2 + d];
        float uv = u[idx * D2 + d];
        float du = dv * uv;
        const float4* Bp = (const float4*)(xdbl + idx * 64 + 32);
        const float4* Cp = (const float4*)(xdbl + idx * 64 + 48);
        float4 B0 = Bp[0], B1 = Bp[1], B2 = Bp[2], B3 = Bp[3];
        float4 C0 = Cp[0], C1 = Cp[1], C2 = Cp[2], C3 = Cp[3];
        float Bn[16] = {B0.x, B0.y, B0.z, B0.w, B1.x, B1.y, B1.z, B1.w,
                        B2.x, B2.y, B2.z, B2.w, B3.x, B3.y, B3.z, B3.w};
        float Cn[16] = {C0.x, C0.y, C0.z, C0.w, C1.x, C1.y, C1.z, C1.w,
                        C2.x, C2.y, C2.z, C2.w, C3.x, C3.y, C3.z, C3.w};
        float y = Dd * uv;
        #pragma unroll
        for (int n = 0; n < NSTATE; n++) {
            h[n] = __expf(dv * A[n]) * h[n] + du * Bn[n];
            y += h[n] * Cn[n];
        }
        outbuf[idx * DINNER + d] = f2bf(y);
    }
}

// ---------------------------------------------------------------------------
// Host-side launch
// ---------------------------------------------------------------------------
extern "C" void kernel_launch(void* const* d_in, const int* in_sizes, int n_in,
                              void* d_out, int out_size, void* d_ws, size_t ws_size,
                              hipStream_t stream)
{
    const float* x         = (const float*)d_in[0];
    const float* ln1_w     = (const float*)d_in[1];
    const float* ln1_b     = (const float*)d_in[2];
    const float* in_proj_w = (const float*)d_in[3];
    const float* conv_x_w  = (const float*)d_in[4];
    const float* conv_z_w  = (const float*)d_in[5];
    const float* x_proj_w  = (const float*)d_in[6];
    const float* dt_proj_w = (const float*)d_in[7];
    const float* dt_proj_b = (const float*)d_in[8];
    const float* A_log     = (const float*)d_in[9];
    const float* ssm_D     = (const float*)d_in[10];
    const float* out_proj_w= (const float*)d_in[11];
    const float* ln2_w     = (const float*)d_in[12];
    const float* ln2_b     = (const float*)d_in[13];
    const float* fc1_w     = (const float*)d_in[14];
    const float* fc1_b     = (const float*)d_in[15];
    const float* fc2_w     = (const float*)d_in[16];
    const float* fc2_b     = (const float*)d_in[17];
    float* out = (float*)d_out;

    // ---- workspace layout (bytes) ----
    char* p = (char*)d_ws;
    unsigned short* wbf_inproj  = (unsigned short*)(p);              // 1,048,576
    unsigned short* wbf_xproj   = (unsigned short*)(p + 1048576);    //    65,536
    unsigned short* wbf_dtproj  = (unsigned short*)(p + 1114112);    //    32,768
    unsigned short* wbf_outproj = (unsigned short*)(p + 1146880);    // 1,048,576
    unsigned short* wbf_fc1     = (unsigned short*)(p + 2195456);    // 2,097,152
    unsigned short* wbf_fc2     = (unsigned short*)(p + 4292608);    // 2,097,152
    char* dyn = p + 6389760;
    unsigned short* xn_bf   = (unsigned short*)(dyn);                 // 8,388,608 (reused as h2)
    unsigned short* xz_bf   = (unsigned short*)(dyn + 8388608);       // 16,777,216 (reused as mlp1)
    float*          xh_f32  = (float*)(dyn + 41943040);               // 16,777,216
    float*          scanS   = (float*)(dyn + 58720256);               // 4,194,304
    float*          scanP   = (float*)(dyn + 62914560);               // 4,194,304
    unsigned short* xh_bf   = (unsigned short*)(dyn + 67108864);      // 8,388,608
    unsigned short* outbuf  = (unsigned short*)(dyn + 75497472);      // 16,777,216
    float*          xdbl_f32= (float*)(dyn + 92274688);               // 2,097,152
    unsigned short* xdbl_bf = (unsigned short*)(dyn + 94371840);      // 1,048,576
    float*          delta_f = (float*)(dyn + 95420416);               // 16,777,216
    float*          hin     = (float*)(dyn + 112197632);              // 4,194,304
    float*          h_f32   = (float*)(dyn + 116391936);              // 16,777,216
    unsigned short* h2_bf   = xn_bf;                                  // overlay
    unsigned short* mlp1_bf = xz_bf;                                  // overlay (xz dead after conv)

    // 1. weights -> bf16
    cvt_weights<<<12480, 256, 0, stream>>>(in_proj_w, x_proj_w, dt_proj_w,
        out_proj_w, fc1_w, fc2_w, wbf_inproj, wbf_xproj, wbf_dtproj,
        wbf_outproj, wbf_fc1, wbf_fc2);

    // 2. LN1
    ln_kernel<<<MROWS, 256, 0, stream>>>(x, ln1_w, ln1_b, xn_bf);

    // 3. in_proj: xz = xn @ W^T  (8192 x 1024, K=512) -> bf16
    //    MI=64: 128*16 = 2048 waves -> 512 blocks
    gemm_rr<M_BF16, 64><<<512, 256, 0, stream>>>(
        xn_bf, DMODEL, wbf_inproj, DMODEL, MROWS, DINNER, DMODEL,
        nullptr, xz_bf, DINNER, nullptr, nullptr);

    // 4. depthwise conv + SiLU
    conv_silu<<<16384, 256, 0, stream>>>(xz_bf, conv_x_w, conv_z_w,
        xh_f32, xh_bf, outbuf);

    // 5. x_proj: x_dbl = xh @ W^T  (8192 x 64, K=512) -> fp32 + bf16
    //    MI=16: 512*1 = 512 waves -> 128 blocks
    gemm_rr<M_F32_BF16, 16><<<128, 256, 0, stream>>>(
        xh_bf, D2, wbf_xproj, D2, MROWS, 64, D2,
        xdbl_f32, xdbl_bf, 64, nullptr, nullptr);

    // 6. dt_proj + softplus: delta = softplus(dt @ W^T + b)  (8192 x 512, K=32)
    //    MI=32: 256*8 = 2048 waves -> 512 blocks
    gemm_rr<M_SOFTPLUS_F32, 32><<<512, 256, 0, stream>>>(
        xdbl_bf, 64, wbf_dtproj, 32, MROWS, D2, 32,
        delta_f, nullptr, D2, dt_proj_b, nullptr);

    // 7-9. selective scan
    scan_phase1<<<256, 256, 0, stream>>>(delta_f, xh_f32, xdbl_f32, A_log,
        scanS, scanP);
    scan_phase2<<<256, 256, 0, stream>>>(scanS, scanP, hin);
    scan_phase3<<<256, 256, 0, stream>>>(delta_f, xh_f32, xdbl_f32, hin,
        A_log, ssm_D, outbuf);

    // 10. out_proj + residual: h = x + outbuf @ W^T  (8192 x 512, K=1024)
    //     MI=32: 256*8 = 2048 waves -> 512 blocks
    gemm_rr<M_RES_F32, 32><<<512, 256, 0, stream>>>(
        outbuf, DINNER, wbf_outproj, DINNER, MROWS, DMODEL, DINNER,
        h_f32, nullptr, DMODEL, nullptr, x);

    // 11. LN2
    ln_kernel<<<MROWS, 256, 0, stream>>>(h_f32, ln2_w, ln2_b, h2_bf);

    // 12. fc1 + bias + exact GELU -> bf16  (8192 x 2048, K=512)
    //     MI=64: 128*32 = 4096 waves -> 1024 blocks
    gemm_rr<M_GELU_BF16, 64><<<1024, 256, 0, stream>>>(
        h2_bf, DMODEL, wbf_fc1, DMODEL, MROWS, HIDDEN, DMODEL,
        nullptr, mlp1_bf, HIDDEN, fc1_b, nullptr);

    // 13. fc2 + bias + residual -> d_out  (8192 x 512, K=2048)
    //     MI=32: 256*8 = 2048 waves -> 512 blocks
    gemm_rr<M_BIAS_RES_F32, 32><<<512, 256, 0, stream>>>(
        mlp1_bf, HIDDEN, wbf_fc2, HIDDEN, MROWS, DMODEL, HIDDEN,
        out, nullptr, DMODEL, fc2_b, h_f32);
}

// Round 4
// 366.087 us; speedup vs baseline: 1.3854x; 1.3854x over previous
//
#include <hip/hip_runtime.h>
#include <stdint.h>

// ---------------------------------------------------------------------------
// Mamba block on MI355X (gfx950).  B=8, L=1024, D_MODEL=512, D_INNER=1024,
// D2=512, DT_RANK=32, N_STATE=16, K_CONV=4, HIDDEN=2048.  M = B*L = 8192.
//
// R4: packed-fragment dataflow. Every GEMM operand (A and W) is stored in
// MFMA-fragment order:  (m,k) -> (m/16)*16*K + (k/32)*512 + lane*8 + (k%8),
// lane = ((k>>3)&3)*16 + (m&15).  Staging is contiguous 1 KB global_load_lds
// per instruction; LDS reads at lane*16B are conflict-free fragments; all
// epilogues go through an LDS transpose to coalesced (or packed) stores.
// ---------------------------------------------------------------------------

#define MROWS 8192
#define LSEQ 1024
#define DMODEL 512
#define DINNER 1024
#define D2 512
#define NSTATE 16
#define HIDDEN 2048
#define NCHUNK 16
#define LCHUNK 64

typedef unsigned short us;
typedef short short8 __attribute__((ext_vector_type(8)));
typedef float floatx4 __attribute__((ext_vector_type(4)));

__device__ __forceinline__ us f2bf(float f) {
    unsigned int u = __float_as_uint(f);
    u = (u + 0x7fffu + ((u >> 16) & 1u)) >> 16;
    return (us)u;
}
__device__ __forceinline__ float bf2f(us u) {
    return __uint_as_float(((unsigned int)u) << 16);
}

// Async global->LDS 16B/lane copy (HW: lds dst uniform base + lane*16).
__device__ __forceinline__ void g2lds16(const void* g, void* l) {
    typedef __attribute__((address_space(1))) void GV;
    typedef __attribute__((address_space(3))) void LV;
    GV* gp = (GV*)(uintptr_t)g;
    LV* lp = (LV*)(uint32_t)(uintptr_t)l;
    __builtin_amdgcn_global_load_lds(gp, lp, 16, 0, 0);
}

// ---------------------------------------------------------------------------
// Pack fp32 weight W(N,K) -> bf16 fragment order. One 16B slot per thread-σ.
// slot σ: lane=σ&63, ks=(σ>>6)%(K/32), g=σ/((K/32)*64);
// reads W[g*16+(lane&15)][ks*32+(lane>>4)*8 .. +8]; dst is linear: dst+σ*8.
// ---------------------------------------------------------------------------
__device__ __forceinline__ void pack_slot(const float* __restrict__ w,
                                          us* __restrict__ dst, int K, int sig)
{
    int lane = sig & 63;
    int KS = K >> 5;
    int ks = (sig >> 6) % KS;
    int g = sig / (KS << 6);
    const float* src = w + (size_t)(g * 16 + (lane & 15)) * K
                         + ks * 32 + (lane >> 4) * 8;
    short8 o;
    #pragma unroll
    for (int e = 0; e < 8; e++) o[e] = (short)f2bf(src[e]);
    *(short8*)(dst + (size_t)sig * 8) = o;
}

__global__ __launch_bounds__(256) void cvt_pack6(
    const float* __restrict__ w0, const float* __restrict__ w1,
    const float* __restrict__ w2, const float* __restrict__ w3,
    const float* __restrict__ w4, const float* __restrict__ w5,
    us* __restrict__ o0, us* __restrict__ o1, us* __restrict__ o2,
    us* __restrict__ o3, us* __restrict__ o4, us* __restrict__ o5)
{
    int bx = blockIdx.x, t = threadIdx.x;
    if (bx < 256)        pack_slot(w0, o0, 512,  bx * 256 + t);          // in_proj 1024x512
    else if (bx < 272)   pack_slot(w1, o1, 512,  (bx - 256) * 256 + t);  // x_proj 64x512
    else if (bx < 280)   pack_slot(w2, o2, 32,   (bx - 272) * 256 + t);  // dt_proj 512x32
    else if (bx < 536)   pack_slot(w3, o3, 1024, (bx - 280) * 256 + t);  // out_proj 512x1024
    else if (bx < 1048)  pack_slot(w4, o4, 512,  (bx - 536) * 256 + t);  // fc1 2048x512
    else                 pack_slot(w5, o5, 2048, (bx - 1048) * 256 + t); // fc2 512x2048
}

// ---------------------------------------------------------------------------
// LayerNorm over 512 ch; one block per 16-row group; writes packed bf16.
// ---------------------------------------------------------------------------
__global__ __launch_bounds__(256) void ln_pack(
    const float* __restrict__ x, const float* __restrict__ w,
    const float* __restrict__ b, us* __restrict__ outp)
{
    int g = blockIdx.x, t = threadIdx.x;
    __shared__ float T[16][516];
    __shared__ float mu[16], rs[16];
    const float* src = x + (size_t)g * 16 * DMODEL;
    #pragma unroll
    for (int p = 0; p < 8; p++) {
        int idx4 = p * 256 + t;
        int row = idx4 >> 7, c = (idx4 & 127) << 2;
        float4 v = *(const float4*)(src + (size_t)row * DMODEL + c);
        *(float4*)&T[row][c] = v;
    }
    __syncthreads();
    int r = t >> 4, i = t & 15;
    float s = 0.f, ss = 0.f;
    #pragma unroll
    for (int c = 0; c < 32; c++) {
        float v = T[r][c * 16 + i];
        s += v; ss += v * v;
    }
    #pragma unroll
    for (int off = 8; off > 0; off >>= 1) {
        s += __shfl_down(s, off, 16);
        ss += __shfl_down(ss, off, 16);
    }
    if (i == 0) {
        float m = s * (1.f / DMODEL);
        mu[r] = m;
        rs[r] = rsqrtf(ss * (1.f / DMODEL) - m * m + 1e-5f);
    }
    __syncthreads();
    #pragma unroll
    for (int s0 = 0; s0 < 4; s0++) {
        int sig = t * 4 + s0;
        int lane = sig & 63, ks = sig >> 6;
        int lr = lane & 15, lq = lane >> 4;
        int k0 = ks * 32 + lq * 8;
        float m = mu[lr], r2 = rs[lr];
        short8 o;
        #pragma unroll
        for (int e = 0; e < 8; e++)
            o[e] = (short)f2bf((T[lr][k0 + e] - m) * r2 * w[k0 + e] + b[k0 + e]);
        *(short8*)(outp + (size_t)g * 8192 + sig * 8) = o;
    }
}

// ---------------------------------------------------------------------------
// Packed-operand MFMA GEMM.  C(M,N) = A(M,K) * W(N,K)^T, fp32 acc.
// BM=64, BN in {64,128}, BK=32, 256 threads = 4 waves; wave tile 32 x BN/2.
// Epilogue through LDS transpose: row-major f32 / row-major bf16 / packed.
// ---------------------------------------------------------------------------
#define MO_ROWBF16 0      // outB row-major bf16
#define MO_F32_PACK 1     // outF row f32 + outP packed bf16
#define MO_SOFTPLUS 2     // outF = softplus(v + bias)
#define MO_RES 3          // outF = v + res
#define MO_GELU_PACK 4    // outP = gelu(v + bias) packed
#define MO_BIAS_RES 5     // outF = v + bias + res

template <int MODE, int BN>
__global__ __launch_bounds__(256) void gemm_pk(
    const us* __restrict__ Ap, int KA,
    const us* __restrict__ Bp, int KB, int Kloop,
    int Nout, int ldc,
    float* __restrict__ outF, us* __restrict__ outB, us* __restrict__ outP,
    const float* __restrict__ bias, const float* __restrict__ res)
{
    constexpr int NBg = BN / 16;      // B groups per block
    constexpr int NJ = BN / 32;       // col-tiles per wave
    constexpr int TS = 4 + NBg;       // staging slots per iter
    constexpr int PS = TS / 4;        // slots per wave
    constexpr int SMSZ = 64 * (BN + 4) * 4;
    __shared__ __align__(16) char smraw[SMSZ];
    us* sA = (us*)smraw;
    us* sB = sA + 2048;
    float (*TT)[BN + 4] = (float (*)[BN + 4])smraw;

    int t = threadIdx.x;
    int lane = t & 63, w = t >> 6;
    int lr = lane & 15, lq = lane >> 4;
    int m0 = blockIdx.x * 64, n0 = blockIdx.y * BN;
    int gA0 = blockIdx.x * 4;
    int gB0 = n0 >> 4;

    floatx4 acc[2][NJ];
    #pragma unroll
    for (int i = 0; i < 2; i++)
        #pragma unroll
        for (int j = 0; j < NJ; j++) acc[i][j] = (floatx4){0.f, 0.f, 0.f, 0.f};

    for (int ks = 0; ks * 32 < Kloop; ks++) {
        #pragma unroll
        for (int s = 0; s < PS; s++) {
            int slot = w * PS + s;
            if (slot < 4)
                g2lds16(Ap + ((size_t)(gA0 + slot) * KA + ks * 32) * 16 + lane * 8,
                        sA + slot * 512);
            else
                g2lds16(Bp + ((size_t)(gB0 + slot - 4) * KB + ks * 32) * 16 + lane * 8,
                        sB + (slot - 4) * 512);
        }
        __syncthreads();
        short8 af[2], bfv[NJ];
        #pragma unroll
        for (int i = 0; i < 2; i++)
            af[i] = *(const short8*)(sA + ((w & 1) * 2 + i) * 512 + lane * 8);
        #pragma unroll
        for (int j = 0; j < NJ; j++)
            bfv[j] = *(const short8*)(sB + ((w >> 1) * NJ + j) * 512 + lane * 8);
        #pragma unroll
        for (int i = 0; i < 2; i++)
            #pragma unroll
            for (int j = 0; j < NJ; j++)
                acc[i][j] = __builtin_amdgcn_mfma_f32_16x16x32_bf16(
                    af[i], bfv[j], acc[i][j], 0, 0, 0);
        __syncthreads();
    }

    // --- epilogue: acc -> LDS transpose tile (C/D: col=lane&15, row=lq*4+r)
    #pragma unroll
    for (int i = 0; i < 2; i++)
        #pragma unroll
        for (int j = 0; j < NJ; j++)
            #pragma unroll
            for (int r = 0; r < 4; r++)
                TT[(w & 1) * 32 + i * 16 + lq * 4 + r]
                  [(w >> 1) * (BN / 2) + j * 16 + lr] = acc[i][j][r];
    __syncthreads();

    if (MODE == MO_F32_PACK || MODE == MO_SOFTPLUS || MODE == MO_RES ||
        MODE == MO_BIAS_RES) {
        constexpr int passes = 64 * BN / 4 / 256;
        #pragma unroll
        for (int p = 0; p < passes; p++) {
            int idx = p * 256 + t;
            int row = idx / (BN / 4);
            int c = (idx % (BN / 4)) * 4;
            float4 v = *(float4*)&TT[row][c];
            int col = n0 + c;
            size_t o = (size_t)(m0 + row) * ldc + col;
            float4 rv = {0, 0, 0, 0}, bv = {0, 0, 0, 0};
            if (MODE == MO_RES || MODE == MO_BIAS_RES) rv = *(const float4*)(res + o);
            if (MODE == MO_SOFTPLUS || MODE == MO_BIAS_RES) bv = *(const float4*)(bias + col);
            float vv[4] = {v.x, v.y, v.z, v.w};
            float rr[4] = {rv.x, rv.y, rv.z, rv.w};
            float bb[4] = {bv.x, bv.y, bv.z, bv.w};
            float oo[4];
            #pragma unroll
            for (int e = 0; e < 4; e++) {
                if (MODE == MO_SOFTPLUS) {
                    float tb = vv[e] + bb[e];
                    oo[e] = (tb > 20.f) ? tb : log1pf(__expf(tb));
                } else if (MODE == MO_RES) {
                    oo[e] = vv[e] + rr[e];
                } else if (MODE == MO_BIAS_RES) {
                    oo[e] = vv[e] + bb[e] + rr[e];
                } else {
                    oo[e] = vv[e];
                }
            }
            float4 ov = {oo[0], oo[1], oo[2], oo[3]};
            *(float4*)(outF + o) = ov;
        }
    }
    if (MODE == MO_ROWBF16) {
        constexpr int passes = 64 * BN / 8 / 256;
        #pragma unroll
        for (int p = 0; p < passes; p++) {
            int idx = p * 256 + t;
            int row = idx / (BN / 8);
            int c = (idx % (BN / 8)) * 8;
            short8 o8;
            #pragma unroll
            for (int e = 0; e < 8; e++) o8[e] = (short)f2bf(TT[row][c + e]);
            *(short8*)(outB + (size_t)(m0 + row) * ldc + n0 + c) = o8;
        }
    }
    if (MODE == MO_F32_PACK || MODE == MO_GELU_PACK) {
        constexpr int passes = 8 * BN / 256;
        #pragma unroll
        for (int p = 0; p < passes; p++) {
            int sig = p * 256 + t;
            int gi = sig / (2 * BN);
            int rem = sig % (2 * BN);
            int ksl = rem >> 6;
            int ln2 = rem & 63;
            int lr2 = ln2 & 15, lq2 = ln2 >> 4;
            int mloc = gi * 16 + lr2;
            int nloc = ksl * 32 + lq2 * 8;
            short8 o8;
            #pragma unroll
            for (int e = 0; e < 8; e++) {
                float vv = TT[mloc][nloc + e];
                if (MODE == MO_GELU_PACK) {
                    float tb = vv + bias[n0 + nloc + e];
                    vv = 0.5f * tb * (1.f + erff(tb * 0.70710678118f));
                }
                o8[e] = (short)f2bf(vv);
            }
            *(short8*)(outP + ((size_t)((m0 >> 4) + gi) * Nout + n0 + ksl * 32) * 16
                       + ln2 * 8) = o8;
        }
    }
}

// ---------------------------------------------------------------------------
// Depthwise conv (K=4, pad 1/2) + SiLU. One block per 16-seq-row group.
// xz row-major bf16 in; out: xh_f32 row-major, xh packed bf16,
// z -> outbuf packed (k >= 512 region of the out_proj A matrix, Kout=1024).
// ---------------------------------------------------------------------------
__global__ __launch_bounds__(256) void conv_pk(
    const us* __restrict__ xz, const float* __restrict__ cwx,
    const float* __restrict__ cwz, float* __restrict__ xh_f,
    us* __restrict__ xh_p, us* __restrict__ outbuf_p)
{
    int bx = blockIdx.x, t = threadIdx.x;
    int b = bx >> 6, g = bx & 63;
    size_t rowbase = (size_t)b * LSEQ;
    // x half -> xh (packed K=512) + row-major f32
    #pragma unroll
    for (int s = 0; s < 4; s++) {
        int sig = t * 4 + s;
        int ks = sig >> 6, lane = sig & 63;
        int lr = lane & 15, lq = lane >> 4;
        int l = g * 16 + lr;
        int d0 = ks * 32 + lq * 8;
        float ax[8] = {0, 0, 0, 0, 0, 0, 0, 0};
        #pragma unroll
        for (int kk = 0; kk < 4; kk++) {
            int ls = l + kk - 1;
            if (ls >= 0 && ls < LSEQ) {
                const us* src = xz + (rowbase + ls) * DINNER + d0;
                #pragma unroll
                for (int e = 0; e < 8; e++)
                    ax[e] += cwx[(d0 + e) * 4 + kk] * bf2f(src[e]);
            }
        }
        short8 o8;
        float vo[8];
        #pragma unroll
        for (int e = 0; e < 8; e++) {
            float v = ax[e];
            v = v / (1.f + __expf(-v));
            vo[e] = v;
            o8[e] = (short)f2bf(v);
        }
        *(short8*)(xh_p + (size_t)bx * 8192 + sig * 8) = o8;
        float* fo = xh_f + (rowbase + l) * D2 + d0;
        float4 f0 = {vo[0], vo[1], vo[2], vo[3]};
        float4 f1 = {vo[4], vo[5], vo[6], vo[7]};
        *(float4*)fo = f0;
        *(float4*)(fo + 4) = f1;
    }
    // z half -> outbuf packed (Kout=1024, k = 512 + d)
    #pragma unroll
    for (int s = 0; s < 4; s++) {
        int sig = t * 4 + s;
        int ks = sig >> 6, lane = sig & 63;
        int lr = lane & 15, lq = lane >> 4;
        int l = g * 16 + lr;
        int d0 = ks * 32 + lq * 8;
        float az[8] = {0, 0, 0, 0, 0, 0, 0, 0};
        #pragma unroll
        for (int kk = 0; kk < 4; kk++) {
            int ls = l + kk - 1;
            if (ls >= 0 && ls < LSEQ) {
                const us* src = xz + (rowbase + ls) * DINNER + 512 + d0;
                #pragma unroll
                for (int e = 0; e < 8; e++)
                    az[e] += cwz[(d0 + e) * 4 + kk] * bf2f(src[e]);
            }
        }
        short8 o8;
        #pragma unroll
        for (int e = 0; e < 8; e++) {
            float v = az[e];
            v = v / (1.f + __expf(-v));
            o8[e] = (short)f2bf(v);
        }
        *(short8*)(outbuf_p + (size_t)bx * 16384 + 8192 + sig * 8) = o8;
    }
}

// ---------------------------------------------------------------------------
// Selective scan, 3-phase chunked linear recurrence (phase3 writes packed y).
// ---------------------------------------------------------------------------
__global__ __launch_bounds__(256) void scan_phase1(
    const float* __restrict__ delta, const float* __restrict__ u,
    const float* __restrict__ xdbl, const float* __restrict__ A_log,
    float* __restrict__ S, float* __restrict__ P)
{
    int bx = blockIdx.x;
    int b = bx >> 5, rem = bx & 31, c = rem >> 1, half = rem & 1;
    int d = half * 256 + threadIdx.x;
    float A[NSTATE], h[NSTATE];
    #pragma unroll
    for (int n = 0; n < NSTATE; n++) {
        A[n] = -__expf(A_log[d * NSTATE + n]);
        h[n] = 0.f;
    }
    float sdt = 0.f;
    int l0 = c * LCHUNK;
    for (int l = l0; l < l0 + LCHUNK; ++l) {
        size_t idx = (size_t)(b * LSEQ + l);
        float dv = delta[idx * D2 + d];
        float uv = u[idx * D2 + d];
        float du = dv * uv;
        const float4* Bp = (const float4*)(xdbl + idx * 64 + 32);
        float4 B0 = Bp[0], B1 = Bp[1], B2 = Bp[2], B3 = Bp[3];
        float Bn[16] = {B0.x, B0.y, B0.z, B0.w, B1.x, B1.y, B1.z, B1.w,
                        B2.x, B2.y, B2.z, B2.w, B3.x, B3.y, B3.z, B3.w};
        sdt += dv;
        #pragma unroll
        for (int n = 0; n < NSTATE; n++)
            h[n] = __expf(dv * A[n]) * h[n] + du * Bn[n];
    }
    size_t o = ((size_t)(b * D2 + d)) * (NCHUNK * NSTATE) + c * NSTATE;
    #pragma unroll
    for (int n = 0; n < NSTATE; n++) {
        S[o + n] = h[n];
        P[o + n] = __expf(sdt * A[n]);
    }
}

__global__ __launch_bounds__(256) void scan_phase2(
    const float* __restrict__ S, const float* __restrict__ P,
    float* __restrict__ hin)
{
    int gid = blockIdx.x * 256 + threadIdx.x;
    int n = gid & 15;
    size_t base = ((size_t)(gid >> 4)) * (NCHUNK * NSTATE) + n;
    float h = 0.f;
    for (int c = 0; c < NCHUNK; c++) {
        size_t o = base + c * NSTATE;
        hin[o] = h;
        h = P[o] * h + S[o];
    }
}

__global__ __launch_bounds__(256) void scan_phase3(
    const float* __restrict__ delta, const float* __restrict__ u,
    const float* __restrict__ xdbl, const float* __restrict__ hin,
    const float* __restrict__ A_log, const float* __restrict__ Dvec,
    us* __restrict__ outbuf_p)
{
    int bx = blockIdx.x;
    int b = bx >> 5, rem = bx & 31, c = rem >> 1, half = rem & 1;
    int t = threadIdx.x;
    int d = half * 256 + t;
    __shared__ us yl[64][264];
    float A[NSTATE], h[NSTATE];
    size_t hb = ((size_t)(b * D2 + d)) * (NCHUNK * NSTATE) + c * NSTATE;
    #pragma unroll
    for (int n = 0; n < NSTATE; n++) {
        A[n] = -__expf(A_log[d * NSTATE + n]);
        h[n] = hin[hb + n];
    }
    float Dd = Dvec[d];
    int l0 = c * LCHUNK;
    for (int l = l0; l < l0 + LCHUNK; ++l) {
        size_t idx = (size_t)(b * LSEQ + l);
        float dv = delta[idx * D2 + d];
        float uv = u[idx * D2 + d];
        float du = dv * uv;
        const float4* Bp = (const float4*)(xdbl + idx * 64 + 32);
        const float4* Cp = (const float4*)(xdbl + idx * 64 + 48);
        float4 B0 = Bp[0], B1 = Bp[1], B2 = Bp[2], B3 = Bp[3];
        float4 C0 = Cp[0], C1 = Cp[1], C2 = Cp[2], C3 = Cp[3];
        float Bn[16] = {B0.x, B0.y, B0.z, B0.w, B1.x, B1.y, B1.z, B1.w,
                        B2.x, B2.y, B2.z, B2.w, B3.x, B3.y, B3.z, B3.w};
        float Cn[16] = {C0.x, C0.y, C0.z, C0.w, C1.x, C1.y, C1.z, C1.w,
                        C2.x, C2.y, C2.z, C2.w, C3.x, C3.y, C3.z, C3.w};
        float y = Dd * uv;
        #pragma unroll
        for (int n = 0; n < NSTATE; n++) {
            h[n] = __expf(dv * A[n]) * h[n] + du * Bn[n];
            y += h[n] * Cn[n];
        }
        yl[l - l0][t] = f2bf(y);
    }
    __syncthreads();
    // packed write: groups g0..g0+3, k-range [half*256, half*256+256)
    int g0 = (b * LSEQ + l0) >> 4;
    #pragma unroll
    for (int s = 0; s < 8; s++) {
        int sig = t * 8 + s;
        int gi = sig >> 9;
        int rem2 = sig & 511;
        int ksl = rem2 >> 6;
        int lane = rem2 & 63;
        int lr = lane & 15, lq = lane >> 4;
        uint4 v = *(uint4*)&yl[gi * 16 + lr][ksl * 32 + lq * 8];
        *(uint4*)(outbuf_p + ((size_t)(g0 + gi) * 1024 + (half * 8 + ksl) * 32) * 16
                  + lane * 8) = v;
    }
}

// ---------------------------------------------------------------------------
// Host-side launch
// ---------------------------------------------------------------------------
extern "C" void kernel_launch(void* const* d_in, const int* in_sizes, int n_in,
                              void* d_out, int out_size, void* d_ws, size_t ws_size,
                              hipStream_t stream)
{
    const float* x         = (const float*)d_in[0];
    const float* ln1_w     = (const float*)d_in[1];
    const float* ln1_b     = (const float*)d_in[2];
    const float* in_proj_w = (const float*)d_in[3];
    const float* conv_x_w  = (const float*)d_in[4];
    const float* conv_z_w  = (const float*)d_in[5];
    const float* x_proj_w  = (const float*)d_in[6];
    const float* dt_proj_w = (const float*)d_in[7];
    const float* dt_proj_b = (const float*)d_in[8];
    const float* A_log     = (const float*)d_in[9];
    const float* ssm_D     = (const float*)d_in[10];
    const float* out_proj_w= (const float*)d_in[11];
    const float* ln2_w     = (const float*)d_in[12];
    const float* ln2_b     = (const float*)d_in[13];
    const float* fc1_w     = (const float*)d_in[14];
    const float* fc1_b     = (const float*)d_in[15];
    const float* fc2_w     = (const float*)d_in[16];
    const float* fc2_b     = (const float*)d_in[17];
    float* out = (float*)d_out;

    char* p = (char*)d_ws;
    us* wp_in  = (us*)(p);                    // 1 MB
    us* wp_x   = (us*)(p + 1048576);          // 64 KB
    us* wp_dt  = (us*)(p + 1114112);          // 32 KB
    us* wp_out = (us*)(p + 1146880);          // 1 MB
    us* wp_f1  = (us*)(p + 2195456);          // 2 MB
    us* wp_f2  = (us*)(p + 4292608);          // 2 MB -> ends 6389760
    us*    xn_p    = (us*)(p + 6389760);      // 8 MB   (reused as h2_p)
    us*    xz      = (us*)(p + 14778368);     // 16 MB  (mlp1_p overlays from here, 32 MB)
    us*    xh_p    = (us*)(p + 31555584);     // 8 MB
    float* xh_f    = (float*)(p + 39944192);  // 16 MB
    us*    outbuf_p= (us*)(p + 56721408);     // 16 MB
    float* xdbl_f  = (float*)(p + 73498624);  // 2 MB
    us*    xdbl_p  = (us*)(p + 75595776);     // 1 MB
    float* delta_f = (float*)(p + 76644352);  // 16 MB
    float* scanS   = (float*)(p + 93421568);  // 4 MB
    float* scanP   = (float*)(p + 97615872);  // 4 MB
    float* hin     = (float*)(p + 101810176); // 4 MB
    float* h_f     = (float*)(p + 106004480); // 16 MB -> ends 122781696
    us*    h2_p    = xn_p;
    us*    mlp1_p  = xz;                      // 32 MB overlay (xz/xh_p/xh_f dead)

    // 1. weights -> packed bf16
    cvt_pack6<<<1560, 256, 0, stream>>>(in_proj_w, x_proj_w, dt_proj_w,
        out_proj_w, fc1_w, fc2_w, wp_in, wp_x, wp_dt, wp_out, wp_f1, wp_f2);

    // 2. LN1 -> xn packed
    ln_pack<<<512, 256, 0, stream>>>(x, ln1_w, ln1_b, xn_p);

    // 3. in_proj (8192x1024, K=512) -> xz row-major bf16
    gemm_pk<MO_ROWBF16, 128><<<dim3(128, 8), 256, 0, stream>>>(
        xn_p, 512, wp_in, 512, 512, 0, DINNER,
        nullptr, xz, nullptr, nullptr, nullptr);

    // 4. conv + SiLU -> xh (f32 row + packed), z -> outbuf packed (k>=512)
    conv_pk<<<512, 256, 0, stream>>>(xz, conv_x_w, conv_z_w, xh_f, xh_p, outbuf_p);

    // 5. x_proj (8192x64, K=512) -> xdbl f32 row + packed bf16 (Kpack=64)
    gemm_pk<MO_F32_PACK, 64><<<dim3(128, 1), 256, 0, stream>>>(
        xh_p, 512, wp_x, 512, 512, 64, 64,
        xdbl_f, nullptr, xdbl_p, nullptr, nullptr);

    // 6. dt_proj (8192x512, K=32) + softplus -> delta f32 row-major
    gemm_pk<MO_SOFTPLUS, 64><<<dim3(128, 8), 256, 0, stream>>>(
        xdbl_p, 64, wp_dt, 32, 32, 0, D2,
        delta_f, nullptr, nullptr, dt_proj_b, nullptr);

    // 7-9. selective scan; phase3 writes y packed into outbuf (k<512)
    scan_phase1<<<256, 256, 0, stream>>>(delta_f, xh_f, xdbl_f, A_log, scanS, scanP);
    scan_phase2<<<256, 256, 0, stream>>>(scanS, scanP, hin);
    scan_phase3<<<512, 256, 0, stream>>>(delta_f, xh_f, xdbl_f, hin, A_log,
        ssm_D, outbuf_p);

    // 10. out_proj (8192x512, K=1024) + residual x -> h f32 row-major
    gemm_pk<MO_RES, 64><<<dim3(128, 8), 256, 0, stream>>>(
        outbuf_p, 1024, wp_out, 1024, 1024, 0, DMODEL,
        h_f, nullptr, nullptr, nullptr, x);

    // 11. LN2 -> h2 packed
    ln_pack<<<512, 256, 0, stream>>>(h_f, ln2_w, ln2_b, h2_p);

    // 12. fc1 (8192x2048, K=512) + bias + GELU -> mlp1 packed (Kpack=2048)
    gemm_pk<MO_GELU_PACK, 128><<<dim3(128, 16), 256, 0, stream>>>(
        h2_p, 512, wp_f1, 512, 512, 2048, HIDDEN,
        nullptr, nullptr, mlp1_p, fc1_b, nullptr);

    // 13. fc2 (8192x512, K=2048) + bias + residual h -> d_out f32
    gemm_pk<MO_BIAS_RES, 64><<<dim3(128, 8), 256, 0, stream>>>(
        mlp1_p, 2048, wp_f2, 2048, 2048, 0, DMODEL,
        out, nullptr, nullptr, fc2_b, h_f);
}